// Round 8
// baseline (743.941 us; speedup 1.0000x reference)
//
#include <hip/hip_runtime.h>

// CRF log-likelihood, round 14b: one wave per batch chain — ZERO barriers,
// zero cross-wave traffic. r8-r13 mapped the multi-wave design space: the
// cheapest 4-wave barrier structure costs ~900 cy/step of sync machinery
// that no scheduling trick removes. This round removes the machinery.
// (r14a failed to compile: cvt_pkrtz returns __fp16x2, not _Float16x2.)
//
// Layout: 512 scan waves (batch x {fwd,bwd}), one 64-thr block each.
// Lane l owns state components 2l, 2l+1. E = exp(trans) lives in 128 VGPRs
// as packed f16 k-pairs (fwd: columns j=2l,2l+1; bwd: rows k=2l,2l+1).
// Per step: state (128 f16 = 64 dwords) broadcast-read from a wave-private
// LDS buffer (16 ds_read_b128, all lanes same addr = conflict-free
// broadcast), 2 outputs/lane via 128 mixed-precision MACs
// ((float)f16*(float)f16+f32 -> v_fma_mix, full rate), renorm by lag-1
// scale s_0 (dword 64 of the buffer), pack f16x2, write 1 dword, private
// lgkmcnt(0) (~40 cy; NO s_barrier anywhere). Double-buffered by step
// parity. Per-batch balanced cut cb=(tfin+1)>>1: no sort, no groups, no
// padding; captures/inject are wave-uniform branches.
//   blocks 0..255   : fwd scan, batch b = bid, t = 1..cb, capture q_cb.
//   blocks 256..511 : bwd scan r_{t-1} = E(u_t.*r_t), start tb0 =
//                     (tfin+4)&~3 with w=1, inject at t-1==tfin, run down
//                     to cb+1, capture r_cb (cb==tfin: ones at init).
//   blocks 512..767 : per-batch unary+binary score (64-lane reduce).
// crf_comb: logZ = ln2*(log2(dot(qcap,rcap)) + Dq + Dr); out = score-logZ.

#define LL   1024
#define TT   128
#define L2E  1.4426950408889634f
#define LN2f 0.6931471805599453f

typedef __attribute__((ext_vector_type(2))) __fp16 h2;
typedef __attribute__((ext_vector_type(2))) float f2;
union h2u { h2 h; unsigned u; };

__device__ __forceinline__ h2 pkh(float lo, float hi) {
#if __has_builtin(__builtin_amdgcn_cvt_pkrtz)
    return __builtin_amdgcn_cvt_pkrtz(lo, hi);
#else
    h2 r; r.x = (__fp16)lo; r.y = (__fp16)hi; return r;
#endif
}
// (float)f16 * (float)f16 + f32 -> v_fma_mix on gfx9+; portable, full rate.
__device__ __forceinline__ float dmix(h2 a, h2 b, float c) {
    c += (float)a.x * (float)b.x;
    c += (float)a.y * (float)b.y;
    return c;
}

template<bool FWD, int PH>
__device__ __forceinline__ void step1(int t, float& Dacc, f2 (&up)[4],
                                      const h2 (&E)[64][2],
                                      unsigned (&lds)[2][128],
                                      const float* pu,
                                      float* capg, float* dcapg,
                                      int cb, int tfin, int lane)
{
    constexpr int CUR  = PH & 1;
    constexpr int NXT  = CUR ^ 1;
    constexpr int SLOT = FWD ? ((1 + PH) & 3) : ((3 - PH) & 3);

    float sprev = __uint_as_float(lds[CUR][64]);
    const uint4* sp = (const uint4*)&lds[CUR][0];

    // u for this step + prefetch 4 ahead (only vmem in the loop)
    float ex0 = __builtin_amdgcn_exp2f(up[SLOT].x * L2E);
    float ex1 = __builtin_amdgcn_exp2f(up[SLOT].y * L2E);
    {
        int tp = FWD ? (t + 4) : (t - 5);
        tp = tp < 0 ? 0 : (tp > LL - 1 ? LL - 1 : tp);
        up[SLOT] = *(const f2*)(pu + (size_t)tp * TT);
    }

    // ---- 2 outputs/lane: 128 MACs as 256 v_fma_mix, 4 partial accs each ----
    float a[4] = {0.f, 0.f, 0.f, 0.f};
    float c[4] = {0.f, 0.f, 0.f, 0.f};
    #pragma unroll
    for (int g = 0; g < 4; ++g) {
        #pragma unroll
        for (int r = 0; r < 4; ++r) {
            uint4 wv = sp[4 * g + r];
            const int k0 = g * 16 + r * 4;
            h2u u0, u1, u2, u3;
            u0.u = wv.x; u1.u = wv.y; u2.u = wv.z; u3.u = wv.w;
            a[g] = dmix(E[k0+0][0], u0.h, a[g]);
            c[g] = dmix(E[k0+0][1], u0.h, c[g]);
            a[g] = dmix(E[k0+1][0], u1.h, a[g]);
            c[g] = dmix(E[k0+1][1], u1.h, c[g]);
            a[g] = dmix(E[k0+2][0], u2.h, a[g]);
            c[g] = dmix(E[k0+2][1], u2.h, c[g]);
            a[g] = dmix(E[k0+3][0], u3.h, a[g]);
            c[g] = dmix(E[k0+3][1], u3.h, c[g]);
        }
    }
    float s0 = (a[0] + a[1]) + (a[2] + a[3]);
    float s1 = (c[0] + c[1]) + (c[2] + c[3]);

    // lag-1 renorm (scale = raw component 0 of previous step, r12 scheme)
    float ci = __builtin_amdgcn_rcpf(sprev);
    float lg = __builtin_amdgcn_logf(sprev);          // v_log_f32 = log2
    bool inj = (!FWD) && (tfin == t - 1);
    float cis  = inj ? 0.f : ci;
    float injf = inj ? 1.f : 0.f;
    Dacc = inj ? 0.f : (Dacc + lg);

    float rv0 = cis * s0 + injf;
    float rv1 = cis * s1 + injf;

    if (!FWD) {
        if (cb == t - 1 && cb != tfin) {              // wave-uniform
            f2 cp; cp.x = rv0; cp.y = rv1;
            *(f2*)(capg + 2 * lane) = cp;
            if (lane == 0) *dcapg = Dacc;
        }
    }

    float ov0 = ex0 * rv0;
    float ov1 = ex1 * rv1;

    if (FWD) {
        if (cb == t) {                                // wave-uniform
            f2 cp; cp.x = ov0; cp.y = ov1;
            *(f2*)(capg + 2 * lane) = cp;
            if (lane == 0) *dcapg = Dacc;
        }
    }

    h2u pk; pk.h = pkh(ov0, ov1);
    lds[NXT][lane] = pk.u;
    if (lane == 0) lds[NXT][64] = __float_as_uint(s0);   // raw s_0 (lane 0 = j0=0)
    asm volatile("s_waitcnt lgkmcnt(0)" ::: "memory");   // wave-private drain
}

__launch_bounds__(64, 1)
__global__ void crf_scan(const float* __restrict__ inputs,
                         const int*   __restrict__ tags,
                         const int*   __restrict__ slens,
                         const float* __restrict__ trans,
                         float* __restrict__ qcap, float* __restrict__ rcap,
                         float* __restrict__ dqv,  float* __restrict__ drv,
                         float* __restrict__ scorebuf)
{
    const int bid  = blockIdx.x;
    const int lane = threadIdx.x;

    // ---------------- score blocks (512..767): 1 batch each ----------------
    if (bid >= 512) {
        const int b = bid - 512;
        const int slen = slens[b];
        const float* inb  = inputs + (size_t)b * LL * TT;
        const int*   tagb = tags + b * LL;
        float sc = 0.f;
        for (int t = lane; t < slen; t += 64) {
            int tg = tagb[t];
            float v = inb[(size_t)t * TT + tg];
            if (t >= 1) v += trans[tagb[t - 1] * TT + tg];
            sc += v;
        }
        #pragma unroll
        for (int off = 32; off > 0; off >>= 1) sc += __shfl_xor(sc, off, 64);
        if (lane == 0) scorebuf[b] = sc;
        return;
    }

    // ---------------- scan blocks: one wave, one batch, one direction ------
    __shared__ __align__(16) unsigned lds[2][128];    // 2 x (64 state + scale)

    const bool isf = bid < 256;
    const int  b   = isf ? bid : bid - 256;

    int sl = slens[b];
    int tfin = sl - 1; if (tfin < 1) tfin = 1;
    const int cb = (tfin + 1) >> 1;                   // per-batch balanced cut

    // E in 128 VGPRs: packed f16 pairs over the reduction index.
    // fwd (E^T alpha): E[kk][s] = (e(trans[2kk][j_s]), e(trans[2kk+1][j_s])),
    //                  j_0 = 2*lane, j_1 = 2*lane+1  (columns)
    // bwd (E w):       E[jj][s] = (e(trans[k_s][2jj]), e(trans[k_s][2jj+1])),
    //                  k_0 = 2*lane, k_1 = 2*lane+1  (rows)
    h2 E[64][2];
    if (isf) {
        #pragma unroll
        for (int kk = 0; kk < 64; ++kk) {
            f2 r0 = *(const f2*)(trans + (size_t)(2 * kk)     * TT + 2 * lane);
            f2 r1 = *(const f2*)(trans + (size_t)(2 * kk + 1) * TT + 2 * lane);
            E[kk][0] = pkh(__builtin_amdgcn_exp2f(r0.x * L2E),
                           __builtin_amdgcn_exp2f(r1.x * L2E));
            E[kk][1] = pkh(__builtin_amdgcn_exp2f(r0.y * L2E),
                           __builtin_amdgcn_exp2f(r1.y * L2E));
        }
    } else {
        #pragma unroll
        for (int jj = 0; jj < 64; ++jj) {
            f2 r0 = *(const f2*)(trans + (size_t)(2 * lane)     * TT + 2 * jj);
            f2 r1 = *(const f2*)(trans + (size_t)(2 * lane + 1) * TT + 2 * jj);
            E[jj][0] = pkh(__builtin_amdgcn_exp2f(r0.x * L2E),
                           __builtin_amdgcn_exp2f(r0.y * L2E));
            E[jj][1] = pkh(__builtin_amdgcn_exp2f(r1.x * L2E),
                           __builtin_amdgcn_exp2f(r1.y * L2E));
        }
    }

    const float* pu = inputs + (size_t)b * LL * TT + 2 * lane;
    float Dacc = 0.f;
    f2 up[4];

    if (isf) {
        // init alpha_0 = exp(in[b][0][:]) -> buf 0; scale = 1
        f2 v0 = *(const f2*)(pu);
        h2u pk0;
        pk0.h = pkh(__builtin_amdgcn_exp2f(v0.x * L2E),
                    __builtin_amdgcn_exp2f(v0.y * L2E));
        lds[0][lane] = pk0.u;
        if (lane == 0) lds[0][64] = __float_as_uint(1.0f);
        #pragma unroll
        for (int s = 1; s <= 4; ++s)
            up[s & 3] = *(const f2*)(pu + (size_t)s * TT);
        asm volatile("s_waitcnt lgkmcnt(0)" ::: "memory");

        float* capg = qcap + (size_t)b * TT;
        #pragma unroll 1
        for (int tb = 1; tb <= cb; tb += 4) {
            step1<true,0>(tb+0, Dacc, up, E, lds, pu, capg, dqv + b, cb, tfin, lane);
            step1<true,1>(tb+1, Dacc, up, E, lds, pu, capg, dqv + b, cb, tfin, lane);
            step1<true,2>(tb+2, Dacc, up, E, lds, pu, capg, dqv + b, cb, tfin, lane);
            step1<true,3>(tb+3, Dacc, up, E, lds, pu, capg, dqv + b, cb, tfin, lane);
        }
    } else {
        // init w = 1; cb == tfin (only tfin==1) captures ones / Dr = 0 here
        lds[0][lane] = 0x3C003C00u;                   // (1.0h, 1.0h)
        if (lane == 0) lds[0][64] = __float_as_uint(1.0f);
        if (cb == tfin) {
            f2 one2; one2.x = 1.f; one2.y = 1.f;
            *(f2*)(rcap + (size_t)b * TT + 2 * lane) = one2;
            if (lane == 0) drv[b] = 0.f;
        }
        const int tb0 = (tfin + 4) & ~3;              // >= tfin+1, == 0 mod 4
        #pragma unroll
        for (int ph = 0; ph < 4; ++ph) {
            int ui = tb0 - 1 - ph;
            ui = ui > LL - 1 ? LL - 1 : (ui < 0 ? 0 : ui);
            up[(3 - ph) & 3] = *(const f2*)(pu + (size_t)ui * TT);
        }
        asm volatile("s_waitcnt lgkmcnt(0)" ::: "memory");

        float* capg = rcap + (size_t)b * TT;
        #pragma unroll 1
        for (int tb = tb0; tb > cb; tb -= 4) {
            step1<false,0>(tb-0, Dacc, up, E, lds, pu, capg, drv + b, cb, tfin, lane);
            step1<false,1>(tb-1, Dacc, up, E, lds, pu, capg, drv + b, cb, tfin, lane);
            step1<false,2>(tb-2, Dacc, up, E, lds, pu, capg, drv + b, cb, tfin, lane);
            step1<false,3>(tb-3, Dacc, up, E, lds, pu, capg, drv + b, cb, tfin, lane);
        }
    }
}

__global__ void crf_comb(const float* __restrict__ qcap, const float* __restrict__ rcap,
                         const float* __restrict__ dqv, const float* __restrict__ drv,
                         const float* __restrict__ scorebuf,
                         float* __restrict__ out) {
    const int tid = threadIdx.x;
    const int r16 = tid >> 4, part = tid & 15;
    const int b = blockIdx.x * 16 + r16;
    const float* qc = qcap + (size_t)b * TT + part * 8;
    const float* rc = rcap + (size_t)b * TT + part * 8;
    float4 a0 = *(const float4*)(qc);
    float4 a1 = *(const float4*)(qc + 4);
    float4 b0 = *(const float4*)(rc);
    float4 b1 = *(const float4*)(rc + 4);
    float s = a0.x*b0.x + a0.y*b0.y + a0.z*b0.z + a0.w*b0.w
            + a1.x*b1.x + a1.y*b1.y + a1.z*b1.z + a1.w*b1.w;
    #pragma unroll
    for (int o = 1; o < 16; o <<= 1) s += __shfl_xor(s, o, 16);
    if (part == 0) {
        float logZ = LN2f * (__builtin_amdgcn_logf(s) + dqv[b] + drv[b]);
        out[b] = scorebuf[b] - logZ;
    }
}

extern "C" void kernel_launch(void* const* d_in, const int* in_sizes, int n_in,
                              void* d_out, int out_size, void* d_ws, size_t ws_size,
                              hipStream_t stream) {
    const float* inputs = (const float*)d_in[0];
    const int*   tags   = (const int*)d_in[1];
    const int*   slens  = (const int*)d_in[2];
    const float* trans  = (const float*)d_in[3];
    float* out = (float*)d_out;

    float* qcap = (float*)d_ws;            // 256*128 f32
    float* rcap = qcap + 32768;            // 256*128 f32
    float* dqv  = rcap + 32768;            // 256
    float* drv  = dqv + 256;               // 256
    float* scorebuf = drv + 256;           // 256

    crf_scan<<<768, 64, 0, stream>>>(inputs, tags, slens, trans,
                                     qcap, rcap, dqv, drv, scorebuf);
    crf_comb<<<16, 256, 0, stream>>>(qcap, rcap, dqv, drv, scorebuf, out);
}